// Round 1
// 1341.885 us; speedup vs baseline: 1.5892x; 1.5892x over previous
//
#include <hip/hip_runtime.h>
#include <hip/hip_bf16.h>

// COLT graph propagation, MI355X (gfx950) — round: logical-byte reduction.
// (1) All gather sources bf16 (q/t converted once) -> gather bytes halved,
//     working set 92 MB = L3-resident.
// (2) Restructured propagate: L1 stores F1(bf16)+inorm only; L2 computes
//     out = base + F1*inorm + l2norm(f2) in ONE write (no acc RMW, no init
//     memcpys). Scene base read as bf16 S16; TL_s gathers bf16 T16 of TL_t.
// (3) Parallel 3-kernel scan (replaces ~100us/build serial exscan); scan
//     writes ptr AND cur (no D2D memcpy); (col,val) packed int2.
// Scratch q16|t16|T16 (107.5 MB) lives in the SL region of d_out (only
// writer SL-L2 runs last). ws stays ~117 MB. All row buffers plain
// row-major; lanes use pair mapping j = 2*lane + 1 + 128p via dword loads.

#define DD 384
#define PW 192            // uints (bf16 pairs) per row; also float2 per row
typedef __hip_bfloat16 bf16;

__device__ __forceinline__ float lo2f(unsigned u) { return __uint_as_float(u << 16); }
__device__ __forceinline__ float hi2f(unsigned u) { return __uint_as_float(u & 0xffff0000u); }
__device__ __forceinline__ unsigned packbf(float a, float b)
{
    union { bf16 h; unsigned short s; } ca, cb;
    ca.h = __float2bfloat16(a); cb.h = __float2bfloat16(b);
    return (unsigned)ca.s | ((unsigned)cb.s << 16);
}

// ---------------- CSR build ----------------

__global__ void hist_kernel(const int* __restrict__ rows, const float* __restrict__ vals,
                            int* __restrict__ cnt, int nnz, int filter)
{
    int e = blockIdx.x * blockDim.x + threadIdx.x;
    if (e >= nnz) return;
    if (filter && vals[e] == 0.0f) return;
    atomicAdd(&cnt[rows[e]], 1);
}

// per-1024-block sums
__global__ void scan1_kernel(const int* __restrict__ cnt, int* __restrict__ bsum, int n)
{
    int i = blockIdx.x * 1024 + threadIdx.x;
    int v = (i < n) ? cnt[i] : 0;
#pragma unroll
    for (int off = 32; off; off >>= 1) v += __shfl_xor(v, off, 64);
    __shared__ int w[16];
    if ((threadIdx.x & 63) == 0) w[threadIdx.x >> 6] = v;
    __syncthreads();
    if (threadIdx.x < 16) {
        int s = w[threadIdx.x];
#pragma unroll
        for (int off = 8; off; off >>= 1) s += __shfl_xor(s, off, 16);
        if (threadIdx.x == 0) bsum[blockIdx.x] = s;
    }
}

// exclusive scan of block sums in-place (nb <= 128); writes total to ptr[n]
__global__ void scan2_kernel(int* __restrict__ b, int nb, int* __restrict__ ptr, int n)
{
    __shared__ int tmp[128];
    int tid = threadIdx.x;
    int v = (tid < nb) ? b[tid] : 0;
    tmp[tid] = v;
    __syncthreads();
    for (int off = 1; off < 128; off <<= 1) {
        int add = (tid >= off) ? tmp[tid - off] : 0;
        __syncthreads();
        tmp[tid] += add;
        __syncthreads();
    }
    if (tid < nb) b[tid] = tmp[tid] - v;
    if (tid == nb - 1) ptr[n] = tmp[tid];
}

// per-block exclusive rescan + offset; writes ptr[i] and cur[i] (same value)
__global__ void scan3_kernel(int* __restrict__ cnt_cur, const int* __restrict__ bofs,
                             int* __restrict__ ptr, int n)
{
    __shared__ int tmp[1024];
    int i = blockIdx.x * 1024 + threadIdx.x;
    int v = (i < n) ? cnt_cur[i] : 0;
    tmp[threadIdx.x] = v;
    __syncthreads();
    for (int off = 1; off < 1024; off <<= 1) {
        int add = (threadIdx.x >= off) ? tmp[threadIdx.x - off] : 0;
        __syncthreads();
        tmp[threadIdx.x] += add;
        __syncthreads();
    }
    if (i < n) {
        int x = bofs[blockIdx.x] + tmp[threadIdx.x] - v;   // exclusive
        ptr[i] = x;
        cnt_cur[i] = x;
    }
}

__global__ void scatter_kernel(const int* __restrict__ rows, const int* __restrict__ cols,
                               const float* __restrict__ vals, const float* __restrict__ vals2,
                               int* __restrict__ cur, int2* __restrict__ cv,
                               float* __restrict__ aux, int nnz, int filter)
{
    int e = blockIdx.x * blockDim.x + threadIdx.x;
    if (e >= nnz) return;
    float v = vals[e];
    if (filter && v == 0.0f) return;
    int pos = atomicAdd(&cur[rows[e]], 1);
    float vs = vals2 ? vals2[e] : v;            // agg: cv carries ago_val
    cv[pos] = make_int2(cols[e], __float_as_int(vs));
    if (aux) aux[pos] = v;                      // agg: dropped vals separately
}

// ---------------- fp32 -> bf16 conversion (8 elems/thread) ----------------

__global__ void to_bf16_kernel(const float* __restrict__ src, unsigned* __restrict__ dst, long n8)
{
    long i = (long)blockIdx.x * blockDim.x + threadIdx.x;
    if (i >= n8) return;
    const float4* s = (const float4*)src + i * 2;
    float4 a = s[0], b = s[1];
    uint4 o;
    o.x = packbf(a.x, a.y); o.y = packbf(a.z, a.w);
    o.z = packbf(b.x, b.y); o.w = packbf(b.z, b.w);
    ((uint4*)dst)[i] = o;
}

// ---------------- gathers (one 64-lane wave per row) ----------------

// Layer 1: f = sum_e v * src[col]; store F1 = bf16(f), inorm = 1/max(||f||,1e-12).
__global__ void gather_l1(const int* __restrict__ ptr, const int2* __restrict__ cv,
                          const unsigned* __restrict__ srcA, const unsigned* __restrict__ srcB,
                          int nsplit, unsigned* __restrict__ F1, float* __restrict__ inorm,
                          int nrows)
{
    long tid = (long)blockIdx.x * blockDim.x + threadIdx.x;
    int row = (int)(tid >> 6);
    if (row >= nrows) return;
    int lane = threadIdx.x & 63;
    int e0 = ptr[row], e1 = ptr[row + 1];
    float f0 = 0.f, f1 = 0.f, f2 = 0.f, f3 = 0.f, f4 = 0.f, f5 = 0.f;
    for (int e = e0; e < e1; ++e) {
        int2 p = cv[e];
        float v = __int_as_float(p.y);
        const unsigned* s = (p.x < nsplit) ? srcA + (size_t)p.x * PW
                                           : srcB + (size_t)(p.x - nsplit) * PW;
        unsigned u0 = s[lane], u1 = s[lane + 64], u2 = s[lane + 128];
        f0 += v * lo2f(u0); f1 += v * hi2f(u0);
        f2 += v * lo2f(u1); f3 += v * hi2f(u1);
        f4 += v * lo2f(u2); f5 += v * hi2f(u2);
    }
    float ss = f0 * f0 + f1 * f1 + f2 * f2 + f3 * f3 + f4 * f4 + f5 * f5;
#pragma unroll
    for (int off = 32; off; off >>= 1) ss += __shfl_xor(ss, off, 64);
    if (lane == 0) inorm[row] = 1.0f / fmaxf(sqrtf(ss), 1e-12f);
    unsigned* Fr = F1 + (size_t)row * PW;
    Fr[lane]       = packbf(f0, f1);
    Fr[lane + 64]  = packbf(f2, f3);
    Fr[lane + 128] = packbf(f4, f5);
}

// Layer 2: f2 = sum_e v * F1[col]; out = base + F1[row]*inorm + l2norm(f2).
// base: row<nsplit -> baseA fp32; else baseB (bf16 if B16B else fp32).
// ST: rows>=nsplit also store bf16(out) to storeT (TL_t copy for TL_s gather).
template <bool B16B, bool ST>
__global__ void gather_l2(const int* __restrict__ ptr, const int2* __restrict__ cv,
                          const unsigned* __restrict__ F1, const float* __restrict__ inorm,
                          const float* __restrict__ baseA, const void* __restrict__ baseB,
                          int nsplit, float* __restrict__ out, unsigned* __restrict__ storeT,
                          int nrows)
{
    long tid = (long)blockIdx.x * blockDim.x + threadIdx.x;
    int row = (int)(tid >> 6);
    if (row >= nrows) return;
    int lane = threadIdx.x & 63;
    int e0 = ptr[row], e1 = ptr[row + 1];
    float f0 = 0.f, f1 = 0.f, f2 = 0.f, f3 = 0.f, f4 = 0.f, f5 = 0.f;
    for (int e = e0; e < e1; ++e) {
        int2 p = cv[e];
        float v = __int_as_float(p.y);
        const unsigned* s = F1 + (size_t)p.x * PW;
        unsigned u0 = s[lane], u1 = s[lane + 64], u2 = s[lane + 128];
        f0 += v * lo2f(u0); f1 += v * hi2f(u0);
        f2 += v * lo2f(u1); f3 += v * hi2f(u1);
        f4 += v * lo2f(u2); f5 += v * hi2f(u2);
    }
    float ss = f0 * f0 + f1 * f1 + f2 * f2 + f3 * f3 + f4 * f4 + f5 * f5;
#pragma unroll
    for (int off = 32; off; off >>= 1) ss += __shfl_xor(ss, off, 64);
    float sc2 = 1.0f / fmaxf(sqrtf(ss), 1e-12f);

    const unsigned* Fr = F1 + (size_t)row * PW;
    float s1 = inorm[row];
    unsigned w0 = Fr[lane], w1 = Fr[lane + 64], w2 = Fr[lane + 128];

    float b0, b1, b2, b3, b4, b5;
    if (row < nsplit) {
        const float2* bp = (const float2*)baseA + (size_t)row * PW;
        float2 x0 = bp[lane], x1 = bp[lane + 64], x2 = bp[lane + 128];
        b0 = x0.x; b1 = x0.y; b2 = x1.x; b3 = x1.y; b4 = x2.x; b5 = x2.y;
    } else if (B16B) {
        const unsigned* bp = (const unsigned*)baseB + (size_t)(row - nsplit) * PW;
        unsigned y0 = bp[lane], y1 = bp[lane + 64], y2 = bp[lane + 128];
        b0 = lo2f(y0); b1 = hi2f(y0); b2 = lo2f(y1); b3 = hi2f(y1); b4 = lo2f(y2); b5 = hi2f(y2);
    } else {
        const float2* bp = (const float2*)baseB + (size_t)(row - nsplit) * PW;
        float2 x0 = bp[lane], x1 = bp[lane + 64], x2 = bp[lane + 128];
        b0 = x0.x; b1 = x0.y; b2 = x1.x; b3 = x1.y; b4 = x2.x; b5 = x2.y;
    }

    float o0 = b0 + lo2f(w0) * s1 + f0 * sc2;
    float o1 = b1 + hi2f(w0) * s1 + f1 * sc2;
    float o2 = b2 + lo2f(w1) * s1 + f2 * sc2;
    float o3 = b3 + hi2f(w1) * s1 + f3 * sc2;
    float o4 = b4 + lo2f(w2) * s1 + f4 * sc2;
    float o5 = b5 + hi2f(w2) * s1 + f5 * sc2;

    float2* op = (float2*)out + (size_t)row * PW;
    op[lane]       = make_float2(o0, o1);
    op[lane + 64]  = make_float2(o2, o3);
    op[lane + 128] = make_float2(o4, o5);
    if (ST && row >= nsplit) {
        unsigned* tp = storeT + (size_t)(row - nsplit) * PW;
        tp[lane]       = packbf(o0, o1);
        tp[lane + 64]  = packbf(o2, o3);
        tp[lane + 128] = packbf(o4, o5);
    }
}

// Plain gather SpMM from bf16 src -> fp32 dstF and/or bf16 dstB.
// val = aux[e] if aux else cv[e].y.
__global__ void gather_p(const int* __restrict__ ptr, const int2* __restrict__ cv,
                         const float* __restrict__ aux, const unsigned* __restrict__ src,
                         float* __restrict__ dstF, unsigned* __restrict__ dstB, int nrows)
{
    long tid = (long)blockIdx.x * blockDim.x + threadIdx.x;
    int row = (int)(tid >> 6);
    if (row >= nrows) return;
    int lane = threadIdx.x & 63;
    int e0 = ptr[row], e1 = ptr[row + 1];
    float f0 = 0.f, f1 = 0.f, f2 = 0.f, f3 = 0.f, f4 = 0.f, f5 = 0.f;
    for (int e = e0; e < e1; ++e) {
        int2 p = cv[e];
        float v = aux ? aux[e] : __int_as_float(p.y);
        const unsigned* s = src + (size_t)p.x * PW;
        unsigned u0 = s[lane], u1 = s[lane + 64], u2 = s[lane + 128];
        f0 += v * lo2f(u0); f1 += v * hi2f(u0);
        f2 += v * lo2f(u1); f3 += v * hi2f(u1);
        f4 += v * lo2f(u2); f5 += v * hi2f(u2);
    }
    if (dstF) {
        float2* dp = (float2*)dstF + (size_t)row * PW;
        dp[lane]       = make_float2(f0, f1);
        dp[lane + 64]  = make_float2(f2, f3);
        dp[lane + 128] = make_float2(f4, f5);
    }
    if (dstB) {
        unsigned* dp = dstB + (size_t)row * PW;
        dp[lane]       = packbf(f0, f1);
        dp[lane + 64]  = packbf(f2, f3);
        dp[lane + 128] = packbf(f4, f5);
    }
}

static inline unsigned gridw(long threads) { return (unsigned)((threads + 255) / 256); }

extern "C" void kernel_launch(void* const* d_in, const int* in_sizes, int n_in,
                              void* d_out, int out_size, void* d_ws, size_t ws_size,
                              hipStream_t stream)
{
    const int NQ = 100000, NT = 20000, NS = 10000;
    const int N1 = NQ + NT;        // queries+tools
    const int N2 = NQ + NS;        // queries+scenes
    const int BIG = 0x7fffffff;

    const float* q     = (const float*)d_in[0];
    const float* t     = (const float*)d_in[1];
    const float* tlv   = (const float*)d_in[2];
    const float* slv   = (const float*)d_in[3];
    const float* aggv  = (const float*)d_in[4];
    const float* aggov = (const float*)d_in[5];
    const int* tlr  = (const int*)d_in[6];
    const int* tlc  = (const int*)d_in[7];
    const int* slr  = (const int*)d_in[8];
    const int* slc  = (const int*)d_in[9];
    const int* aggr = (const int*)d_in[10];
    const int* aggc = (const int*)d_in[11];
    const int tl_nnz  = in_sizes[6];
    const int sl_nnz  = in_sizes[8];
    const int agg_nnz = in_sizes[10];

    // ---- workspace carve (~117 MB) ----
    char* w = (char*)d_ws;
    size_t off = 0;
    auto alloc = [&](size_t bytes) -> void* {
        void* p = w + off;
        off += (bytes + 15) & ~(size_t)15;
        return p;
    };
    unsigned* F1    = (unsigned*)alloc((size_t)N1 * PW * sizeof(unsigned)); // 92.2 MB (N1 >= N2)
    unsigned* S16   = (unsigned*)alloc((size_t)NS * PW * sizeof(unsigned)); // 7.7 MB
    float*    inorm = (float*)   alloc((size_t)N1 * sizeof(float));
    int* tl_ptr = (int*)alloc((size_t)(N1 + 1) * sizeof(int));
    int* tl_cur = (int*)alloc((size_t)(N1 + 1) * sizeof(int));
    int* sl_ptr = (int*)alloc((size_t)(N2 + 1) * sizeof(int));
    int* sl_cur = (int*)alloc((size_t)(N2 + 1) * sizeof(int));
    int* ag_ptr = (int*)alloc((size_t)(NS + 1) * sizeof(int));
    int* ag_cur = (int*)alloc((size_t)(NS + 1) * sizeof(int));
    int* bscr   = (int*)alloc(256 * sizeof(int));
    int2*  tl_cv  = (int2*) alloc((size_t)tl_nnz * sizeof(int2));
    int2*  sl_cv  = (int2*) alloc((size_t)sl_nnz * sizeof(int2));
    int2*  ag_cv  = (int2*) alloc((size_t)agg_nnz * sizeof(int2));
    float* ag_aux = (float*)alloc((size_t)agg_nnz * sizeof(float));

    // ---- output carve (fp32) ----
    float* out = (float*)d_out;
    float* TL  = out;                                  // TL_q | TL_t  (N1*D)
    float* TLs = out + (size_t)N1 * DD;                // TL_s (NS*D)
    float* SL  = TLs + (size_t)NS * DD;                // SL_q | SL_s  (N2*D)

    // bf16 scratch inside the SL region (107.5 MB <= 169 MB); SL-L2 (the only
    // writer of this region) runs last, after all scratch readers.
    unsigned* Xq  = (unsigned*)SL;                     // q16:  NQ*PW
    unsigned* Xt  = Xq + (size_t)NQ * PW;              // t16:  NT*PW
    unsigned* XT  = Xt + (size_t)NT * PW;              // T16:  NT*PW (bf16 TL_t)

    // ---- CSR builds ----
    auto build = [&](const int* r, const int* c, const float* v, const float* v2,
                     int* ptr, int* cur, int2* cv, float* aux, int nnz, int n, int filter) {
        hipMemsetAsync(cur, 0, (size_t)n * sizeof(int), stream);
        hist_kernel<<<gridw(nnz), 256, 0, stream>>>(r, v, cur, nnz, filter);
        int nb = (n + 1023) / 1024;
        scan1_kernel<<<nb, 1024, 0, stream>>>(cur, bscr, n);
        scan2_kernel<<<1, 128, 0, stream>>>(bscr, nb, ptr, n);
        scan3_kernel<<<nb, 1024, 0, stream>>>(cur, bscr, ptr, n);
        scatter_kernel<<<gridw(nnz), 256, 0, stream>>>(r, c, v, v2, cur, cv, aux, nnz, filter);
    };
    build(tlr, tlc, tlv, nullptr, tl_ptr, tl_cur, tl_cv, nullptr, tl_nnz, N1, 1);
    build(slr, slc, slv, nullptr, sl_ptr, sl_cur, sl_cv, nullptr, sl_nnz, N2, 1);
    build(aggr, aggc, aggv, aggov, ag_ptr, ag_cur, ag_cv, ag_aux, agg_nnz, NS, 0);

    // ---- bf16 source conversion: q16 | t16 (contiguous => TL cols need no split) ----
    to_bf16_kernel<<<gridw((long)NQ * 48), 256, 0, stream>>>(q, Xq, (long)NQ * 48);
    to_bf16_kernel<<<gridw((long)NT * 48), 256, 0, stream>>>(t, Xt, (long)NT * 48);

    // ---- TL layer 1: F1 = spmm([q16|t16]), inorm ----
    gather_l1<<<gridw((long)N1 * 64), 256, 0, stream>>>(
        tl_ptr, tl_cv, Xq, Xq, BIG, F1, inorm, N1);

    // ---- S16 = bf16(aggo @ t)  (scene features; cv carries ago_val) ----
    gather_p<<<gridw((long)NS * 64), 256, 0, stream>>>(
        ag_ptr, ag_cv, nullptr, Xt, nullptr, S16, NS);

    // ---- TL layer 2: TL = base(q|t) + F1*inorm + l2norm(spmm(F1)); T16 = bf16(TL_t) ----
    gather_l2<false, true><<<gridw((long)N1 * 64), 256, 0, stream>>>(
        tl_ptr, tl_cv, F1, inorm, q, t, NQ, TL, XT, N1);

    // ---- TL_s = agg(dropped) @ TL_t  (reads T16 with aux=dropped vals) ----
    gather_p<<<gridw((long)NS * 64), 256, 0, stream>>>(
        ag_ptr, ag_cv, ag_aux, XT, TLs, nullptr, NS);

    // ---- SL layer 1: F1 = spmm([q16|S16]), inorm (reuses F1/inorm) ----
    gather_l1<<<gridw((long)N2 * 64), 256, 0, stream>>>(
        sl_ptr, sl_cv, Xq, S16, NQ, F1, inorm, N2);

    // ---- SL layer 2: SL = base(q fp32 | S16 bf16) + F1*inorm + l2norm(spmm(F1)) ----
    // (clobbers the Xq/Xt/XT scratch region — all dead by now)
    gather_l2<true, false><<<gridw((long)N2 * 64), 256, 0, stream>>>(
        sl_ptr, sl_cv, F1, inorm, q, S16, NQ, SL, nullptr, N2);
}